// Round 3
// baseline (3177.202 us; speedup 1.0000x reference)
//
#include <hip/hip_runtime.h>

#define TT   2048
#define BB   512
#define IN_  27
#define HH   64
#define OUTD 26
#define EPSV 1e-5f

typedef float floatx32 __attribute__((ext_vector_type(32)));

__device__ __forceinline__ float bcastf(float v, int lane) {
    return __int_as_float(__builtin_amdgcn_readlane(__float_as_int(v), lane));
}

__device__ __forceinline__ float sigm(float x) {
    return 1.0f / (1.0f + __expf(-x));
}

__device__ __forceinline__ float tanh_fast(float x) {
    float e = __expf(-2.0f * fabsf(x));
    float r = (1.0f - e) / (1.0f + e);
    return copysignf(r, x);
}

// Phase 1: sequential LSTM. ONE WAVE per batch element; lane l owns h[l],c[l]
// and all four gates {i,f,g,o} for h-index l. Cell update is lane-local:
// NO LDS, NO barrier in the timestep loop.
//
// ROUND-2 LESSON (VGPR_Count=200, scratch-resident weights): float arrays of
// 364 elements are NOT promoted to registers by promote-alloca -> every step
// re-read all weights from scratch. Fix: weights live in named
// ext_vector_type(32) SSA values (12 x 32 = 384 VGPRs). Constant-index
// extracts compile to direct register operands; there is no alloca to spill.
// __launch_bounds__(64,1) allows the full 512-VGPR single-wave budget.
__global__ __launch_bounds__(64, 1) void lstm_seq(
    const float* __restrict__ x,     // [T,B,IN]
    const float* __restrict__ W_ih,  // [4H,IN]
    const float* __restrict__ W_hh,  // [4H,H]
    const float* __restrict__ b_ih,  // [4H]
    const float* __restrict__ b_hh,  // [4H]
    float* __restrict__ h_all,       // [tc,B,H] (workspace)
    float* __restrict__ state,       // [2,B,H]  (workspace: h then c)
    int t0, int tc, int first)
{
    const int b = blockIdx.x;
    const int l = threadIdx.x;       // 0..63 = h index

    // ---- weights into vector SSA registers (NOT arrays -> NOT scratch) ----
    // gate rows: j = q*64 + l  (q: 0=i 1=f 2=g 3=o)
    floatx32 wh0a{}, wh0b{}, wh1a{}, wh1b{}, wh2a{}, wh2b{}, wh3a{}, wh3b{};
    floatx32 wi0{}, wi1{}, wi2{}, wi3{};

    {
        // W_hh rows are 64 floats, 256B-aligned: load as float4.
        const float4* Wh4 = (const float4*)W_hh;
#define LOAD_WH(q, va, vb)                                                  \
        {                                                                   \
            const int rowq = ((q) * HH + l) * (HH / 4);                     \
            _Pragma("unroll")                                               \
            for (int k4 = 0; k4 < 8; ++k4) {                                \
                const float4 v = Wh4[rowq + k4];                            \
                (va)[4*k4+0] = v.x; (va)[4*k4+1] = v.y;                     \
                (va)[4*k4+2] = v.z; (va)[4*k4+3] = v.w;                     \
            }                                                               \
            _Pragma("unroll")                                               \
            for (int k4 = 0; k4 < 8; ++k4) {                                \
                const float4 v = Wh4[rowq + 8 + k4];                        \
                (vb)[4*k4+0] = v.x; (vb)[4*k4+1] = v.y;                     \
                (vb)[4*k4+2] = v.z; (vb)[4*k4+3] = v.w;                     \
            }                                                               \
        }
        LOAD_WH(0, wh0a, wh0b)
        LOAD_WH(1, wh1a, wh1b)
        LOAD_WH(2, wh2a, wh2b)
        LOAD_WH(3, wh3a, wh3b)
#undef LOAD_WH
#define LOAD_WI(q, vv)                                                      \
        {                                                                   \
            const int rowq = ((q) * HH + l) * IN_;                          \
            _Pragma("unroll")                                               \
            for (int k = 0; k < IN_; ++k) (vv)[k] = W_ih[rowq + k];         \
        }
        LOAD_WI(0, wi0)
        LOAD_WI(1, wi1)
        LOAD_WI(2, wi2)
        LOAD_WI(3, wi3)
#undef LOAD_WI
    }

    const float bias0 = b_ih[0 * HH + l] + b_hh[0 * HH + l];
    const float bias1 = b_ih[1 * HH + l] + b_hh[1 * HH + l];
    const float bias2 = b_ih[2 * HH + l] + b_hh[2 * HH + l];
    const float bias3 = b_ih[3 * HH + l] + b_hh[3 * HH + l];

    float hv, cv;
    if (first) {
        hv = 0.0f; cv = 0.0f;
    } else {
        hv = state[b * HH + l];
        cv = state[BB * HH + b * HH + l];
    }

    // Prefetch x row for t0 (lanes 0..26; others compute but never use it).
    float xv = (l < IN_) ? x[((size_t)t0 * BB + b) * IN_ + l] : 0.0f;

    float* hout = h_all + (size_t)b * HH + l;

#pragma unroll 1
    for (int tl = 0; tl < tc; ++tl) {
        const int t = t0 + tl;

        // Rotate prefetch: consume xv this step, issue load for t+1 now so
        // its HBM/L2 latency hides under the ~460-instr dot-product below.
        const float xcur = xv;
        int tn = t + 1; if (tn > TT - 1) tn = TT - 1;   // clamp (last step)
        xv = (l < IN_) ? x[((size_t)tn * BB + b) * IN_ + l] : 0.0f;

        float a0 = bias0, a1 = bias1, a2 = bias2, a3 = bias3;

        // h-dot: one readlane broadcast (SGPR) feeds 4 FMAs. Same-accumulator
        // dep spacing is 5 instrs (~10 cyc wave64) > FMA latency: no stall.
#pragma unroll
        for (int k = 0; k < 32; ++k) {
            const float hk = bcastf(hv, k);
            a0 = fmaf(hk, wh0a[k], a0);
            a1 = fmaf(hk, wh1a[k], a1);
            a2 = fmaf(hk, wh2a[k], a2);
            a3 = fmaf(hk, wh3a[k], a3);
        }
#pragma unroll
        for (int k = 0; k < 32; ++k) {
            const float hk = bcastf(hv, 32 + k);
            a0 = fmaf(hk, wh0b[k], a0);
            a1 = fmaf(hk, wh1b[k], a1);
            a2 = fmaf(hk, wh2b[k], a2);
            a3 = fmaf(hk, wh3b[k], a3);
        }
        // x-dot
#pragma unroll
        for (int k = 0; k < IN_; ++k) {
            const float xk = bcastf(xcur, k);
            a0 = fmaf(xk, wi0[k], a0);
            a1 = fmaf(xk, wi1[k], a1);
            a2 = fmaf(xk, wi2[k], a2);
            a3 = fmaf(xk, wi3[k], a3);
        }

        const float gi = sigm(a0);
        const float gf = sigm(a1);
        const float gg = tanh_fast(a2);
        const float go = sigm(a3);

        cv = fmaf(gf, cv, gi * gg);
        hv = go * tanh_fast(cv);

        // coalesced 256B store per wave, fire-and-forget
        *hout = hv;
        hout += (size_t)BB * HH;
    }

    state[b * HH + l] = hv;
    state[BB * HH + b * HH + l] = cv;
}

// Phase 2: per-timestep BatchNorm (batch stats) + locked dropout + maxpool
// over batch + FC. One block per timestep, fully parallel over tc.
// Unchanged from the verified round-0 kernel.
__global__ __launch_bounds__(256, 2) void bn_pool_fc(
    const float* __restrict__ h_all,  // [tc,B,H]
    const float* __restrict__ gamma,  // [H]
    const float* __restrict__ beta,   // [H]
    const float* __restrict__ dmask,  // [B,H]
    const float* __restrict__ pg,     // [T,OUT]
    const float* __restrict__ W_fc,   // [OUT, H+OUT]
    const float* __restrict__ b_fc,   // [OUT]
    float* __restrict__ y,            // [T,OUT]
    int t0, int tc)
{
    const int tl = blockIdx.x;
    const int t = t0 + tl;
    const int tid = threadIdx.x;
    const int g = tid >> 6;      // 4 batch groups
    const int hcol = tid & 63;
    const float* hp = h_all + (size_t)tl * BB * HH;

    __shared__ float s_a[4][HH];
    __shared__ float s_b[4][HH];
    __shared__ float s_scale[HH];
    __shared__ float s_shift[HH];
    __shared__ float s_pool[HH];

    // pass 1: sum and sumsq over batch (coalesced: lane = hcol)
    float sum = 0.0f, sq = 0.0f;
    for (int bb = g; bb < BB; bb += 4) {
        const float v = hp[bb * HH + hcol];
        sum += v;
        sq = fmaf(v, v, sq);
    }
    s_a[g][hcol] = sum;
    s_b[g][hcol] = sq;
    __syncthreads();

    if (tid < HH) {
        const float s  = (s_a[0][tid] + s_a[1][tid]) + (s_a[2][tid] + s_a[3][tid]);
        const float q2 = (s_b[0][tid] + s_b[1][tid]) + (s_b[2][tid] + s_b[3][tid]);
        const float mean = s * (1.0f / BB);
        const float var  = q2 * (1.0f / BB) - mean * mean;  // biased var
        const float rs = rsqrtf(var + EPSV);
        const float sc = rs * gamma[tid];
        s_scale[tid] = sc;
        s_shift[tid] = beta[tid] - mean * sc;
    }
    __syncthreads();

    // pass 2: normalize + locked dropout + max over batch
    const float sc = s_scale[hcol];
    const float sh = s_shift[hcol];
    float m = -3.0e38f;
    for (int bb = g; bb < BB; bb += 4) {
        const float v = hp[bb * HH + hcol];
        const float hd = fmaf(v, sc, sh) * dmask[bb * HH + hcol];
        m = fmaxf(m, hd);
    }
    s_a[g][hcol] = m;
    __syncthreads();
    if (tid < HH) {
        s_pool[tid] = fmaxf(fmaxf(s_a[0][tid], s_a[1][tid]),
                            fmaxf(s_a[2][tid], s_a[3][tid]));
    }
    __syncthreads();

    // FC: y[t, o] = b_fc[o] + W_fc[o, 0:64].pool + W_fc[o, 64:90].pg[t]
    if (tid < OUTD) {
        float acc = b_fc[tid];
        const float* w = W_fc + tid * (HH + OUTD);
#pragma unroll
        for (int k = 0; k < HH; ++k) acc = fmaf(w[k], s_pool[k], acc);
#pragma unroll
        for (int k = 0; k < OUTD; ++k) acc = fmaf(w[HH + k], pg[t * OUTD + k], acc);
        y[t * OUTD + tid] = acc;
    }
}

extern "C" void kernel_launch(void* const* d_in, const int* in_sizes, int n_in,
                              void* d_out, int out_size, void* d_ws, size_t ws_size,
                              hipStream_t stream)
{
    const float* x     = (const float*)d_in[0];   // [T,B,IN]
    const float* pg    = (const float*)d_in[1];   // [T,OUT]
    const float* W_ih  = (const float*)d_in[2];   // [4H,IN]
    const float* W_hh  = (const float*)d_in[3];   // [4H,H]
    const float* b_ih  = (const float*)d_in[4];
    const float* b_hh  = (const float*)d_in[5];
    const float* gamma = (const float*)d_in[6];
    const float* beta  = (const float*)d_in[7];
    const float* W_fc  = (const float*)d_in[8];   // [OUT,H+OUT]
    const float* b_fc  = (const float*)d_in[9];
    const float* dmask = (const float*)d_in[10];  // [B,H]
    float* y = (float*)d_out;

    // Workspace: h_all[chunkT, B, H] fp32 + carried state h,c [2,B,H].
    const size_t state_bytes = 2ull * BB * HH * sizeof(float);
    const size_t per_t = (size_t)BB * HH * sizeof(float);
    size_t avail = (ws_size > state_bytes) ? (ws_size - state_bytes) : 0;
    int chunkT = (int)(avail / per_t);
    if (chunkT > TT) chunkT = TT;
    if (chunkT < 1) chunkT = 1;

    float* h_all = (float*)d_ws;
    float* state = (float*)((char*)d_ws + (size_t)chunkT * per_t);

    int first = 1;
    for (int t0 = 0; t0 < TT; t0 += chunkT) {
        int tc = TT - t0;
        if (tc > chunkT) tc = chunkT;
        lstm_seq<<<BB, 64, 0, stream>>>(x, W_ih, W_hh, b_ih, b_hh,
                                        h_all, state, t0, tc, first);
        bn_pool_fc<<<tc, 256, 0, stream>>>(h_all, gamma, beta, dmask, pg,
                                           W_fc, b_fc, y, t0, tc);
        first = 0;
    }
}

// Round 4
// 2902.139 us; speedup vs baseline: 1.0948x; 1.0948x over previous
//
#include <hip/hip_runtime.h>

#define TT   2048
#define BB   512
#define IN_  27
#define HH   64
#define OUTD 26
#define EPSV 1e-5f

typedef float floatx32 __attribute__((ext_vector_type(32)));

__device__ __forceinline__ float bcastf(float v, int lane) {
    return __int_as_float(__builtin_amdgcn_readlane(__float_as_int(v), lane));
}

__device__ __forceinline__ float sigm(float x) {
    return 1.0f / (1.0f + __expf(-x));
}

__device__ __forceinline__ float tanh_fast(float x) {
    float e = __expf(-2.0f * fabsf(x));
    float r = (1.0f - e) / (1.0f + e);
    return copysignf(r, x);
}

// Phase 1: sequential LSTM. TWO waves per batch element, TWO gates per wave.
//
// ROUND-3 LESSON: VALU can address only 256 arch VGPRs. The 1-wave/4-gate
// design needs 384 weight regs -> unavoidable scratch spill (VGPR_Count
// stuck at 200, weights re-read every step; 3035us). Round-0's 4-wave
// design spilled W_hh too (VGPR=56: promote-alloca caps at 32 dwords).
// This version is sized to ACTUALLY fit: 2 gates/wave = 182 weight floats
// in six floatx32 SSA vectors (~220 VGPRs total, register-resident).
//
// Per step per wave: 64 readlane + 128 FMA (h-dot, each broadcast feeds 2
// FMAs) + pipelined x-dot for t+1 (81 instrs) hiding the LDS exchange
// latency + 1 ds_write_b64 + 1 barrier + 1 ds_read_b64. Cell update is
// computed redundantly by both waves (each keeps full hv,cv per lane).
__global__ __launch_bounds__(128, 1) void lstm_seq(
    const float* __restrict__ x,     // [T,B,IN]
    const float* __restrict__ W_ih,  // [4H,IN]
    const float* __restrict__ W_hh,  // [4H,H]
    const float* __restrict__ b_ih,  // [4H]
    const float* __restrict__ b_hh,  // [4H]
    float* __restrict__ h_all,       // [tc,B,H] (workspace)
    float* __restrict__ state,       // [2,B,H]  (workspace: h then c)
    int t0, int tc, int first)
{
    const int b   = blockIdx.x;
    const int wid = threadIdx.x >> 6;   // 0: gates {i,f}   1: gates {g,o}
    const int l   = threadIdx.x & 63;   // h index

    // gate rows owned by this wave: jA = (2*wid)*64 + l, jB = (2*wid+1)*64 + l
    const int jA = (2 * wid) * HH + l;
    const int jB = (2 * wid + 1) * HH + l;

    // ---- weights into SSA vector registers (fits: 6*32=192 VGPRs) ----
    floatx32 whA0{}, whA1{}, whB0{}, whB1{};  // W_hh rows jA, jB (k 0..31 / 32..63)
    floatx32 wiA{}, wiB{};                    // W_ih rows jA, jB (k 0..26)
    {
        const float4* WhA = (const float4*)(W_hh + jA * HH);
        const float4* WhB = (const float4*)(W_hh + jB * HH);
#pragma unroll
        for (int k4 = 0; k4 < 8; ++k4) {
            const float4 va = WhA[k4];
            whA0[4*k4+0] = va.x; whA0[4*k4+1] = va.y;
            whA0[4*k4+2] = va.z; whA0[4*k4+3] = va.w;
            const float4 vb = WhB[k4];
            whB0[4*k4+0] = vb.x; whB0[4*k4+1] = vb.y;
            whB0[4*k4+2] = vb.z; whB0[4*k4+3] = vb.w;
        }
#pragma unroll
        for (int k4 = 0; k4 < 8; ++k4) {
            const float4 va = WhA[8 + k4];
            whA1[4*k4+0] = va.x; whA1[4*k4+1] = va.y;
            whA1[4*k4+2] = va.z; whA1[4*k4+3] = va.w;
            const float4 vb = WhB[8 + k4];
            whB1[4*k4+0] = vb.x; whB1[4*k4+1] = vb.y;
            whB1[4*k4+2] = vb.z; whB1[4*k4+3] = vb.w;
        }
#pragma unroll
        for (int k = 0; k < IN_; ++k) wiA[k] = W_ih[jA * IN_ + k];
#pragma unroll
        for (int k = 0; k < IN_; ++k) wiB[k] = W_ih[jB * IN_ + k];
    }
    const float biasA = b_ih[jA] + b_hh[jA];
    const float biasB = b_ih[jB] + b_hh[jB];

    float hv, cv;
    if (first) {
        hv = 0.0f; cv = 0.0f;
    } else {
        hv = state[b * HH + l];
        cv = state[BB * HH + b * HH + l];
    }

    // exchange buffer: [dbuf][wave][lane] -> (actA, actB). float2 keeps the
    // LDS access 2-way bank aliased (free). Double-buffered -> 1 barrier/step.
    __shared__ float2 exch[2][2][64];

    // Prefetch x row for t0; compute its x-dot partials before the loop.
    float xv = (l < IN_) ? x[((size_t)t0 * BB + b) * IN_ + l] : 0.0f;
    float xa = 0.0f, xb = 0.0f;
    {
#pragma unroll
        for (int k = 0; k < IN_; ++k) {
            const float xk = bcastf(xv, k);
            xa = fmaf(xk, wiA[k], xa);
            xb = fmaf(xk, wiB[k], xb);
        }
    }
    // prefetch x for t0+1
    {
        int tn = t0 + 1; if (tn > TT - 1) tn = TT - 1;
        xv = (l < IN_) ? x[((size_t)tn * BB + b) * IN_ + l] : 0.0f;
    }

    float* hout = h_all + (size_t)b * HH + l;

#pragma unroll 1
    for (int tl = 0; tl < tc; ++tl) {
        const int t = t0 + tl;

        // gate pre-activations: bias + x-dot (pipelined last iter) + h-dot
        float a0 = biasA + xa;
        float a1 = biasB + xb;
#pragma unroll
        for (int k = 0; k < 32; ++k) {
            const float hk = bcastf(hv, k);
            a0 = fmaf(hk, whA0[k], a0);
            a1 = fmaf(hk, whB0[k], a1);
        }
#pragma unroll
        for (int k = 0; k < 32; ++k) {
            const float hk = bcastf(hv, 32 + k);
            a0 = fmaf(hk, whA1[k], a0);
            a1 = fmaf(hk, whB1[k], a1);
        }

        // activations for this wave's two gates (branch is wave-uniform)
        const float act0 = (wid == 0) ? sigm(a0) : tanh_fast(a0);  // i | g
        const float act1 = sigm(a1);                               // f | o

        exch[tl & 1][wid][l] = make_float2(act0, act1);
        __syncthreads();

        // Issue partner read, then hide its latency under next step's x-dot.
        const float2 p = exch[tl & 1][wid ^ 1][l];

        // x-dot for t+1 (uses xv prefetched one step ago), then rotate the
        // global prefetch to t+2.
        const float xcur = xv;
        float nxa = 0.0f, nxb = 0.0f;
#pragma unroll
        for (int k = 0; k < IN_; ++k) {
            const float xk = bcastf(xcur, k);
            nxa = fmaf(xk, wiA[k], nxa);
            nxb = fmaf(xk, wiB[k], nxb);
        }
        int tn = t + 2; if (tn > TT - 1) tn = TT - 1;
        xv = (l < IN_) ? x[((size_t)tn * BB + b) * IN_ + l] : 0.0f;
        xa = nxa; xb = nxb;

        float gi, gf, gg, go;
        if (wid == 0) { gi = act0; gf = act1; gg = p.x; go = p.y; }
        else          { gi = p.x;  gf = p.y;  gg = act0; go = act1; }

        cv = fmaf(gf, cv, gi * gg);
        hv = go * tanh_fast(cv);

        if (wid == 0) {
            *hout = hv;                    // coalesced 256B store per wave
            hout += (size_t)BB * HH;
        }
        // no second barrier: next step writes the OTHER exch buffer; this
        // buffer is re-written only after the NEXT barrier, by which time
        // the partner's read has long completed (it feeds this step's cell).
    }

    if (wid == 0) {
        state[b * HH + l] = hv;
        state[BB * HH + b * HH + l] = cv;
    }
}

// Phase 2: per-timestep BatchNorm (batch stats) + locked dropout + maxpool
// over batch + FC. One block per timestep, fully parallel over tc.
// Unchanged from the verified round-0 kernel.
__global__ __launch_bounds__(256, 2) void bn_pool_fc(
    const float* __restrict__ h_all,  // [tc,B,H]
    const float* __restrict__ gamma,  // [H]
    const float* __restrict__ beta,   // [H]
    const float* __restrict__ dmask,  // [B,H]
    const float* __restrict__ pg,     // [T,OUT]
    const float* __restrict__ W_fc,   // [OUT, H+OUT]
    const float* __restrict__ b_fc,   // [OUT]
    float* __restrict__ y,            // [T,OUT]
    int t0, int tc)
{
    const int tl = blockIdx.x;
    const int t = t0 + tl;
    const int tid = threadIdx.x;
    const int g = tid >> 6;      // 4 batch groups
    const int hcol = tid & 63;
    const float* hp = h_all + (size_t)tl * BB * HH;

    __shared__ float s_a[4][HH];
    __shared__ float s_b[4][HH];
    __shared__ float s_scale[HH];
    __shared__ float s_shift[HH];
    __shared__ float s_pool[HH];

    // pass 1: sum and sumsq over batch (coalesced: lane = hcol)
    float sum = 0.0f, sq = 0.0f;
    for (int bb = g; bb < BB; bb += 4) {
        const float v = hp[bb * HH + hcol];
        sum += v;
        sq = fmaf(v, v, sq);
    }
    s_a[g][hcol] = sum;
    s_b[g][hcol] = sq;
    __syncthreads();

    if (tid < HH) {
        const float s  = (s_a[0][tid] + s_a[1][tid]) + (s_a[2][tid] + s_a[3][tid]);
        const float q2 = (s_b[0][tid] + s_b[1][tid]) + (s_b[2][tid] + s_b[3][tid]);
        const float mean = s * (1.0f / BB);
        const float var  = q2 * (1.0f / BB) - mean * mean;  // biased var
        const float rs = rsqrtf(var + EPSV);
        const float sc = rs * gamma[tid];
        s_scale[tid] = sc;
        s_shift[tid] = beta[tid] - mean * sc;
    }
    __syncthreads();

    // pass 2: normalize + locked dropout + max over batch
    const float sc = s_scale[hcol];
    const float sh = s_shift[hcol];
    float m = -3.0e38f;
    for (int bb = g; bb < BB; bb += 4) {
        const float v = hp[bb * HH + hcol];
        const float hd = fmaf(v, sc, sh) * dmask[bb * HH + hcol];
        m = fmaxf(m, hd);
    }
    s_a[g][hcol] = m;
    __syncthreads();
    if (tid < HH) {
        s_pool[tid] = fmaxf(fmaxf(s_a[0][tid], s_a[1][tid]),
                            fmaxf(s_a[2][tid], s_a[3][tid]));
    }
    __syncthreads();

    // FC: y[t, o] = b_fc[o] + W_fc[o, 0:64].pool + W_fc[o, 64:90].pg[t]
    if (tid < OUTD) {
        float acc = b_fc[tid];
        const float* w = W_fc + tid * (HH + OUTD);
#pragma unroll
        for (int k = 0; k < HH; ++k) acc = fmaf(w[k], s_pool[k], acc);
#pragma unroll
        for (int k = 0; k < OUTD; ++k) acc = fmaf(w[HH + k], pg[t * OUTD + k], acc);
        y[t * OUTD + tid] = acc;
    }
}

extern "C" void kernel_launch(void* const* d_in, const int* in_sizes, int n_in,
                              void* d_out, int out_size, void* d_ws, size_t ws_size,
                              hipStream_t stream)
{
    const float* x     = (const float*)d_in[0];   // [T,B,IN]
    const float* pg    = (const float*)d_in[1];   // [T,OUT]
    const float* W_ih  = (const float*)d_in[2];   // [4H,IN]
    const float* W_hh  = (const float*)d_in[3];   // [4H,H]
    const float* b_ih  = (const float*)d_in[4];
    const float* b_hh  = (const float*)d_in[5];
    const float* gamma = (const float*)d_in[6];
    const float* beta  = (const float*)d_in[7];
    const float* W_fc  = (const float*)d_in[8];   // [OUT,H+OUT]
    const float* b_fc  = (const float*)d_in[9];
    const float* dmask = (const float*)d_in[10];  // [B,H]
    float* y = (float*)d_out;

    // Workspace: h_all[chunkT, B, H] fp32 + carried state h,c [2,B,H].
    const size_t state_bytes = 2ull * BB * HH * sizeof(float);
    const size_t per_t = (size_t)BB * HH * sizeof(float);
    size_t avail = (ws_size > state_bytes) ? (ws_size - state_bytes) : 0;
    int chunkT = (int)(avail / per_t);
    if (chunkT > TT) chunkT = TT;
    if (chunkT < 1) chunkT = 1;

    float* h_all = (float*)d_ws;
    float* state = (float*)((char*)d_ws + (size_t)chunkT * per_t);

    int first = 1;
    for (int t0 = 0; t0 < TT; t0 += chunkT) {
        int tc = TT - t0;
        if (tc > chunkT) tc = chunkT;
        lstm_seq<<<BB, 128, 0, stream>>>(x, W_ih, W_hh, b_ih, b_hh,
                                         h_all, state, t0, tc, first);
        bn_pool_fc<<<tc, 256, 0, stream>>>(h_all, gamma, beta, dmask, pg,
                                           W_fc, b_fc, y, t0, tc);
        first = 0;
    }
}

// Round 5
// 2890.655 us; speedup vs baseline: 1.0991x; 1.0040x over previous
//
#include <hip/hip_runtime.h>

#define TT   2048
#define BB   512
#define IN_  27
#define HH   64
#define OUTD 26
#define EPSV 1e-5f

typedef float floatx16 __attribute__((ext_vector_type(16)));

__device__ __forceinline__ float bcastf(float v, int lane) {
    return __int_as_float(__builtin_amdgcn_readlane(__float_as_int(v), lane));
}

__device__ __forceinline__ float sigm(float x) {
    return 1.0f / (1.0f + __expf(-x));
}

__device__ __forceinline__ float tanh_fast(float x) {
    float e = __expf(-2.0f * fabsf(x));
    float r = (1.0f - e) / (1.0f + e);
    return copysignf(r, x);
}

// Phase 1: sequential LSTM. TWO waves per batch element, TWO gates per wave.
//
// ROUND-4 LESSON: the compiler refuses to keep loop-invariant weight loads
// live (VGPR=108 vs ~230 demanded) because loads from const __restrict__
// memory are re-executable: it re-loads W_hh from L1/L2 inside the loop
// every timestep (invisible in FETCH_SIZE since W is cache-resident, but
// ~2x the instruction stream + load latency at 1-2 waves/SIMD).
// FIX: launder the weight vectors through opaque `asm volatile ("" : "+v")`
// once after init. The defs are then unanalyzable -> re-loading is
// impossible; keep-live (~240 VGPR < 256 VALU-addressable) beats
// spill-to-scratch at loop frequency 2048 in the allocator's cost model.
__global__ __launch_bounds__(128, 1) void lstm_seq(
    const float* __restrict__ x,     // [T,B,IN]
    const float* __restrict__ W_ih,  // [4H,IN]
    const float* __restrict__ W_hh,  // [4H,H]
    const float* __restrict__ b_ih,  // [4H]
    const float* __restrict__ b_hh,  // [4H]
    float* __restrict__ h_all,       // [tc,B,H] (workspace)
    float* __restrict__ state,       // [2,B,H]  (workspace: h then c)
    int t0, int tc, int first)
{
    const int b   = blockIdx.x;
    const int wid = threadIdx.x >> 6;   // 0: gates {i,f}   1: gates {g,o}
    const int l   = threadIdx.x & 63;   // h index

    // gate rows owned by this wave
    const int jA = (2 * wid) * HH + l;
    const int jB = (2 * wid + 1) * HH + l;

    // ---- weights into 12 x floatx16 SSA tuples (192 VGPRs) ----
    floatx16 whA0, whA1, whA2, whA3;   // W_hh row jA, k = 0..15,16..31,32..47,48..63
    floatx16 whB0, whB1, whB2, whB3;   // W_hh row jB
    floatx16 wiA0, wiA1, wiB0, wiB1;   // W_ih rows jA,jB (k 0..15 / 16..26, tail padded)

    {
        const float4* WhA = (const float4*)(W_hh + jA * HH);
        const float4* WhB = (const float4*)(W_hh + jB * HH);
        auto ld16 = [](const float4* p) {
            floatx16 r;
#pragma unroll
            for (int i = 0; i < 4; ++i) {
                const float4 v = p[i];
                r[4 * i + 0] = v.x; r[4 * i + 1] = v.y;
                r[4 * i + 2] = v.z; r[4 * i + 3] = v.w;
            }
            return r;
        };
        whA0 = ld16(WhA + 0);  whA1 = ld16(WhA + 4);
        whA2 = ld16(WhA + 8);  whA3 = ld16(WhA + 12);
        whB0 = ld16(WhB + 0);  whB1 = ld16(WhB + 4);
        whB2 = ld16(WhB + 8);  whB3 = ld16(WhB + 12);

        const float* piA = W_ih + jA * IN_;
        const float* piB = W_ih + jB * IN_;
        floatx16 a{}, b2{}, c{}, d{};
#pragma unroll
        for (int k = 0; k < 16; ++k) { a[k] = piA[k]; c[k] = piB[k]; }
#pragma unroll
        for (int k = 0; k < IN_ - 16; ++k) { b2[k] = piA[16 + k]; d[k] = piB[16 + k]; }
        wiA0 = a; wiA1 = b2; wiB0 = c; wiB1 = d;
    }

    // Opaque launder: after this, the weight tuples cannot be re-materialized
    // from memory — the allocator must keep them live in VGPRs.
    asm volatile("" : "+v"(whA0), "+v"(whA1), "+v"(whA2), "+v"(whA3),
                      "+v"(whB0), "+v"(whB1), "+v"(whB2), "+v"(whB3),
                      "+v"(wiA0), "+v"(wiA1), "+v"(wiB0), "+v"(wiB1));

    const float biasA = b_ih[jA] + b_hh[jA];
    const float biasB = b_ih[jB] + b_hh[jB];

    float hv, cv;
    if (first) {
        hv = 0.0f; cv = 0.0f;
    } else {
        hv = state[b * HH + l];
        cv = state[BB * HH + b * HH + l];
    }

    // exchange buffer: [dbuf][wave][lane] -> (actA, actB). Double-buffered
    // -> exactly one barrier per step.
    __shared__ float2 exch[2][2][64];

    // Prefetch x row for t0; compute its x-dot partials before the loop.
    float xv = (l < IN_) ? x[((size_t)t0 * BB + b) * IN_ + l] : 0.0f;
    float xa = 0.0f, xb = 0.0f;
    {
#pragma unroll
        for (int k = 0; k < 16; ++k) {
            const float xk = bcastf(xv, k);
            xa = fmaf(xk, wiA0[k], xa);
            xb = fmaf(xk, wiB0[k], xb);
        }
#pragma unroll
        for (int k = 0; k < IN_ - 16; ++k) {
            const float xk = bcastf(xv, 16 + k);
            xa = fmaf(xk, wiA1[k], xa);
            xb = fmaf(xk, wiB1[k], xb);
        }
    }
    {
        int tn = t0 + 1; if (tn > TT - 1) tn = TT - 1;
        xv = (l < IN_) ? x[((size_t)tn * BB + b) * IN_ + l] : 0.0f;
    }

    float* hout = h_all + (size_t)b * HH + l;

#pragma unroll 1
    for (int tl = 0; tl < tc; ++tl) {
        const int t = t0 + tl;

        // gate pre-activations: bias + x-dot (pipelined last iter) + h-dot.
        // One readlane broadcast feeds 2 FMAs.
        float a0 = biasA + xa;
        float a1 = biasB + xb;
#pragma unroll
        for (int k = 0; k < 16; ++k) {
            const float hk = bcastf(hv, k);
            a0 = fmaf(hk, whA0[k], a0);
            a1 = fmaf(hk, whB0[k], a1);
        }
#pragma unroll
        for (int k = 0; k < 16; ++k) {
            const float hk = bcastf(hv, 16 + k);
            a0 = fmaf(hk, whA1[k], a0);
            a1 = fmaf(hk, whB1[k], a1);
        }
#pragma unroll
        for (int k = 0; k < 16; ++k) {
            const float hk = bcastf(hv, 32 + k);
            a0 = fmaf(hk, whA2[k], a0);
            a1 = fmaf(hk, whB2[k], a1);
        }
#pragma unroll
        for (int k = 0; k < 16; ++k) {
            const float hk = bcastf(hv, 48 + k);
            a0 = fmaf(hk, whA3[k], a0);
            a1 = fmaf(hk, whB3[k], a1);
        }

        // activations for this wave's two gates (branch is wave-uniform)
        const float act0 = (wid == 0) ? sigm(a0) : tanh_fast(a0);  // i | g
        const float act1 = sigm(a1);                               // f | o

        exch[tl & 1][wid][l] = make_float2(act0, act1);
        __syncthreads();

        // Issue partner read, then hide its latency under next step's x-dot.
        const float2 p = exch[tl & 1][wid ^ 1][l];

        const float xcur = xv;
        float nxa = 0.0f, nxb = 0.0f;
#pragma unroll
        for (int k = 0; k < 16; ++k) {
            const float xk = bcastf(xcur, k);
            nxa = fmaf(xk, wiA0[k], nxa);
            nxb = fmaf(xk, wiB0[k], nxb);
        }
#pragma unroll
        for (int k = 0; k < IN_ - 16; ++k) {
            const float xk = bcastf(xcur, 16 + k);
            nxa = fmaf(xk, wiA1[k], nxa);
            nxb = fmaf(xk, wiB1[k], nxb);
        }
        int tn = t + 2; if (tn > TT - 1) tn = TT - 1;
        xv = (l < IN_) ? x[((size_t)tn * BB + b) * IN_ + l] : 0.0f;
        xa = nxa; xb = nxb;

        float gi, gf, gg, go;
        if (wid == 0) { gi = act0; gf = act1; gg = p.x; go = p.y; }
        else          { gi = p.x;  gf = p.y;  gg = act0; go = act1; }

        cv = fmaf(gf, cv, gi * gg);
        hv = go * tanh_fast(cv);

        if (wid == 0) {
            *hout = hv;                    // coalesced 256B store per wave
            hout += (size_t)BB * HH;
        }
        // no second barrier: next step writes the OTHER exch buffer; this
        // one is only re-written after the NEXT barrier.
    }

    if (wid == 0) {
        state[b * HH + l] = hv;
        state[BB * HH + b * HH + l] = cv;
    }
}

// Phase 2: per-timestep BatchNorm (batch stats) + locked dropout + maxpool
// over batch + FC. One block per timestep, fully parallel over tc.
// Unchanged from the verified round-0 kernel.
__global__ __launch_bounds__(256, 2) void bn_pool_fc(
    const float* __restrict__ h_all,  // [tc,B,H]
    const float* __restrict__ gamma,  // [H]
    const float* __restrict__ beta,   // [H]
    const float* __restrict__ dmask,  // [B,H]
    const float* __restrict__ pg,     // [T,OUT]
    const float* __restrict__ W_fc,   // [OUT, H+OUT]
    const float* __restrict__ b_fc,   // [OUT]
    float* __restrict__ y,            // [T,OUT]
    int t0, int tc)
{
    const int tl = blockIdx.x;
    const int t = t0 + tl;
    const int tid = threadIdx.x;
    const int g = tid >> 6;      // 4 batch groups
    const int hcol = tid & 63;
    const float* hp = h_all + (size_t)tl * BB * HH;

    __shared__ float s_a[4][HH];
    __shared__ float s_b[4][HH];
    __shared__ float s_scale[HH];
    __shared__ float s_shift[HH];
    __shared__ float s_pool[HH];

    // pass 1: sum and sumsq over batch (coalesced: lane = hcol)
    float sum = 0.0f, sq = 0.0f;
    for (int bb = g; bb < BB; bb += 4) {
        const float v = hp[bb * HH + hcol];
        sum += v;
        sq = fmaf(v, v, sq);
    }
    s_a[g][hcol] = sum;
    s_b[g][hcol] = sq;
    __syncthreads();

    if (tid < HH) {
        const float s  = (s_a[0][tid] + s_a[1][tid]) + (s_a[2][tid] + s_a[3][tid]);
        const float q2 = (s_b[0][tid] + s_b[1][tid]) + (s_b[2][tid] + s_b[3][tid]);
        const float mean = s * (1.0f / BB);
        const float var  = q2 * (1.0f / BB) - mean * mean;  // biased var
        const float rs = rsqrtf(var + EPSV);
        const float sc = rs * gamma[tid];
        s_scale[tid] = sc;
        s_shift[tid] = beta[tid] - mean * sc;
    }
    __syncthreads();

    // pass 2: normalize + locked dropout + max over batch
    const float sc = s_scale[hcol];
    const float sh = s_shift[hcol];
    float m = -3.0e38f;
    for (int bb = g; bb < BB; bb += 4) {
        const float v = hp[bb * HH + hcol];
        const float hd = fmaf(v, sc, sh) * dmask[bb * HH + hcol];
        m = fmaxf(m, hd);
    }
    s_a[g][hcol] = m;
    __syncthreads();
    if (tid < HH) {
        s_pool[tid] = fmaxf(fmaxf(s_a[0][tid], s_a[1][tid]),
                            fmaxf(s_a[2][tid], s_a[3][tid]));
    }
    __syncthreads();

    // FC: y[t, o] = b_fc[o] + W_fc[o, 0:64].pool + W_fc[o, 64:90].pg[t]
    if (tid < OUTD) {
        float acc = b_fc[tid];
        const float* w = W_fc + tid * (HH + OUTD);
#pragma unroll
        for (int k = 0; k < HH; ++k) acc = fmaf(w[k], s_pool[k], acc);
#pragma unroll
        for (int k = 0; k < OUTD; ++k) acc = fmaf(w[HH + k], pg[t * OUTD + k], acc);
        y[t * OUTD + tid] = acc;
    }
}

extern "C" void kernel_launch(void* const* d_in, const int* in_sizes, int n_in,
                              void* d_out, int out_size, void* d_ws, size_t ws_size,
                              hipStream_t stream)
{
    const float* x     = (const float*)d_in[0];   // [T,B,IN]
    const float* pg    = (const float*)d_in[1];   // [T,OUT]
    const float* W_ih  = (const float*)d_in[2];   // [4H,IN]
    const float* W_hh  = (const float*)d_in[3];   // [4H,H]
    const float* b_ih  = (const float*)d_in[4];
    const float* b_hh  = (const float*)d_in[5];
    const float* gamma = (const float*)d_in[6];
    const float* beta  = (const float*)d_in[7];
    const float* W_fc  = (const float*)d_in[8];   // [OUT,H+OUT]
    const float* b_fc  = (const float*)d_in[9];
    const float* dmask = (const float*)d_in[10];  // [B,H]
    float* y = (float*)d_out;

    // Workspace: h_all[chunkT, B, H] fp32 + carried state h,c [2,B,H].
    const size_t state_bytes = 2ull * BB * HH * sizeof(float);
    const size_t per_t = (size_t)BB * HH * sizeof(float);
    size_t avail = (ws_size > state_bytes) ? (ws_size - state_bytes) : 0;
    int chunkT = (int)(avail / per_t);
    if (chunkT > TT) chunkT = TT;
    if (chunkT < 1) chunkT = 1;

    float* h_all = (float*)d_ws;
    float* state = (float*)((char*)d_ws + (size_t)chunkT * per_t);

    int first = 1;
    for (int t0 = 0; t0 < TT; t0 += chunkT) {
        int tc = TT - t0;
        if (tc > chunkT) tc = chunkT;
        lstm_seq<<<BB, 128, 0, stream>>>(x, W_ih, W_hh, b_ih, b_hh,
                                         h_all, state, t0, tc, first);
        bn_pool_fc<<<tc, 256, 0, stream>>>(h_all, gamma, beta, dmask, pg,
                                           W_fc, b_fc, y, t0, tc);
        first = 0;
    }
}

// Round 6
// 2293.290 us; speedup vs baseline: 1.3854x; 1.2605x over previous
//
#include <hip/hip_runtime.h>

#define TT   2048
#define BB   512
#define IN_  27
#define HH   64
#define OUTD 26
#define EPSV 1e-5f

__device__ __forceinline__ float bcastf(float v, int lane) {
    return __int_as_float(__builtin_amdgcn_readlane(__float_as_int(v), lane));
}

__device__ __forceinline__ float sigm(float x) {
    return 1.0f / (1.0f + __expf(-x));
}

__device__ __forceinline__ float tanh_fast(float x) {
    float e = __expf(-2.0f * fabsf(x));
    float r = (1.0f - e) / (1.0f + e);
    return copysignf(r, x);
}

// Phase 1: sequential LSTM. FOUR waves per batch element, ONE gate per wave
// (round-0 geometry), but with: (1) weights held as 91 NAMED SCALAR floats,
// laundered via scalar "+v" asm so re-materialization from memory is
// impossible and there is no register-tuple contiguity pressure;
// (2) ONE barrier per step (double-buffered acts exchange);
// (3) x-dot for t+1 software-pipelined into the LDS-read shadow.
//
// Register-allocator bracketing from rounds 0-5: demand 27/lane kept,
// 182+/lane in 512-bit tuples refused (VGPR stuck at ~110 => weights
// re-loaded from L1 every step). This probes 91/lane in scalar SSA form,
// where VGPR_Count is an unambiguous success signal (~130 = live).
__global__ __launch_bounds__(256, 2) void lstm_seq(
    const float* __restrict__ x,     // [T,B,IN]
    const float* __restrict__ W_ih,  // [4H,IN]
    const float* __restrict__ W_hh,  // [4H,H]
    const float* __restrict__ b_ih,  // [4H]
    const float* __restrict__ b_hh,  // [4H]
    float* __restrict__ h_all,       // [tc,B,H] (workspace)
    float* __restrict__ state,       // [2,B,H]  (workspace: h then c)
    int t0, int tc, int first)
{
    const int b   = blockIdx.x;
    const int wid = threadIdx.x >> 6;   // gate: 0=i 1=f 2=g 3=o
    const int l   = threadIdx.x & 63;   // h index
    const int j   = wid * HH + l;       // gate row

    // ---- W_hh row j: 64 named scalars (compiler merges into dwordx4) ----
    const float* Wp = W_hh + j * HH;
    float wh0 =Wp[0],  wh1 =Wp[1],  wh2 =Wp[2],  wh3 =Wp[3];
    float wh4 =Wp[4],  wh5 =Wp[5],  wh6 =Wp[6],  wh7 =Wp[7];
    float wh8 =Wp[8],  wh9 =Wp[9],  wh10=Wp[10], wh11=Wp[11];
    float wh12=Wp[12], wh13=Wp[13], wh14=Wp[14], wh15=Wp[15];
    float wh16=Wp[16], wh17=Wp[17], wh18=Wp[18], wh19=Wp[19];
    float wh20=Wp[20], wh21=Wp[21], wh22=Wp[22], wh23=Wp[23];
    float wh24=Wp[24], wh25=Wp[25], wh26=Wp[26], wh27=Wp[27];
    float wh28=Wp[28], wh29=Wp[29], wh30=Wp[30], wh31=Wp[31];
    float wh32=Wp[32], wh33=Wp[33], wh34=Wp[34], wh35=Wp[35];
    float wh36=Wp[36], wh37=Wp[37], wh38=Wp[38], wh39=Wp[39];
    float wh40=Wp[40], wh41=Wp[41], wh42=Wp[42], wh43=Wp[43];
    float wh44=Wp[44], wh45=Wp[45], wh46=Wp[46], wh47=Wp[47];
    float wh48=Wp[48], wh49=Wp[49], wh50=Wp[50], wh51=Wp[51];
    float wh52=Wp[52], wh53=Wp[53], wh54=Wp[54], wh55=Wp[55];
    float wh56=Wp[56], wh57=Wp[57], wh58=Wp[58], wh59=Wp[59];
    float wh60=Wp[60], wh61=Wp[61], wh62=Wp[62], wh63=Wp[63];

    // ---- W_ih row j: 27 named scalars ----
    const float* Ip = W_ih + j * IN_;
    float wi0 =Ip[0],  wi1 =Ip[1],  wi2 =Ip[2],  wi3 =Ip[3];
    float wi4 =Ip[4],  wi5 =Ip[5],  wi6 =Ip[6],  wi7 =Ip[7];
    float wi8 =Ip[8],  wi9 =Ip[9],  wi10=Ip[10], wi11=Ip[11];
    float wi12=Ip[12], wi13=Ip[13], wi14=Ip[14], wi15=Ip[15];
    float wi16=Ip[16], wi17=Ip[17], wi18=Ip[18], wi19=Ip[19];
    float wi20=Ip[20], wi21=Ip[21], wi22=Ip[22], wi23=Ip[23];
    float wi24=Ip[24], wi25=Ip[25], wi26=Ip[26];

    // ---- scalar launder: defs become opaque; remat from memory impossible ----
    asm volatile("" : "+v"(wh0), "+v"(wh1), "+v"(wh2), "+v"(wh3),
                      "+v"(wh4), "+v"(wh5), "+v"(wh6), "+v"(wh7),
                      "+v"(wh8), "+v"(wh9), "+v"(wh10), "+v"(wh11),
                      "+v"(wh12), "+v"(wh13), "+v"(wh14), "+v"(wh15));
    asm volatile("" : "+v"(wh16), "+v"(wh17), "+v"(wh18), "+v"(wh19),
                      "+v"(wh20), "+v"(wh21), "+v"(wh22), "+v"(wh23),
                      "+v"(wh24), "+v"(wh25), "+v"(wh26), "+v"(wh27),
                      "+v"(wh28), "+v"(wh29), "+v"(wh30), "+v"(wh31));
    asm volatile("" : "+v"(wh32), "+v"(wh33), "+v"(wh34), "+v"(wh35),
                      "+v"(wh36), "+v"(wh37), "+v"(wh38), "+v"(wh39),
                      "+v"(wh40), "+v"(wh41), "+v"(wh42), "+v"(wh43),
                      "+v"(wh44), "+v"(wh45), "+v"(wh46), "+v"(wh47));
    asm volatile("" : "+v"(wh48), "+v"(wh49), "+v"(wh50), "+v"(wh51),
                      "+v"(wh52), "+v"(wh53), "+v"(wh54), "+v"(wh55),
                      "+v"(wh56), "+v"(wh57), "+v"(wh58), "+v"(wh59),
                      "+v"(wh60), "+v"(wh61), "+v"(wh62), "+v"(wh63));
    asm volatile("" : "+v"(wi0), "+v"(wi1), "+v"(wi2), "+v"(wi3),
                      "+v"(wi4), "+v"(wi5), "+v"(wi6), "+v"(wi7),
                      "+v"(wi8), "+v"(wi9), "+v"(wi10), "+v"(wi11),
                      "+v"(wi12), "+v"(wi13), "+v"(wi14), "+v"(wi15));
    asm volatile("" : "+v"(wi16), "+v"(wi17), "+v"(wi18), "+v"(wi19),
                      "+v"(wi20), "+v"(wi21), "+v"(wi22), "+v"(wi23),
                      "+v"(wi24), "+v"(wi25), "+v"(wi26));

    const float bias = b_ih[j] + b_hh[j];

    float hv, cv;
    if (first) {
        hv = 0.0f; cv = 0.0f;
    } else {
        hv = state[b * HH + l];
        cv = state[BB * HH + b * HH + l];
    }

    // acts[dbuf][gate][lane]; double-buffered -> exactly 1 barrier/step
    __shared__ float acts[2][4][HH];

    // h-dot / x-dot unrolled with 4 rotating accumulators
#define HD(k, acc) acc = fmaf(bcastf(hv, k), wh##k, acc);
#define XD(k, acc) acc = fmaf(bcastf(xcur, k), wi##k, acc);

    // Prefetch x for t0; compute its x-dot before the loop.
    float xv = (l < IN_) ? x[((size_t)t0 * BB + b) * IN_ + l] : 0.0f;
    float xpart;
    {
        const float xcur = xv;
        float p0 = 0.0f, p1 = 0.0f, p2 = 0.0f, p3 = 0.0f;
        XD(0,p0)  XD(1,p1)  XD(2,p2)  XD(3,p3)
        XD(4,p0)  XD(5,p1)  XD(6,p2)  XD(7,p3)
        XD(8,p0)  XD(9,p1)  XD(10,p2) XD(11,p3)
        XD(12,p0) XD(13,p1) XD(14,p2) XD(15,p3)
        XD(16,p0) XD(17,p1) XD(18,p2) XD(19,p3)
        XD(20,p0) XD(21,p1) XD(22,p2) XD(23,p3)
        XD(24,p0) XD(25,p1) XD(26,p2)
        xpart = (p0 + p1) + (p2 + p3);
    }
    {   // prefetch x for t0+1
        int tn = t0 + 1; if (tn > TT - 1) tn = TT - 1;
        xv = (l < IN_) ? x[((size_t)tn * BB + b) * IN_ + l] : 0.0f;
    }

    float* hout = h_all + (size_t)b * HH + l;

#pragma unroll 1
    for (int tl = 0; tl < tc; ++tl) {
        const int t = t0 + tl;

        // gate pre-activation: bias + x-dot (pipelined) + h-dot
        float a0 = bias + xpart, a1 = 0.0f, a2 = 0.0f, a3 = 0.0f;
        HD(0,a0)  HD(1,a1)  HD(2,a2)  HD(3,a3)
        HD(4,a0)  HD(5,a1)  HD(6,a2)  HD(7,a3)
        HD(8,a0)  HD(9,a1)  HD(10,a2) HD(11,a3)
        HD(12,a0) HD(13,a1) HD(14,a2) HD(15,a3)
        HD(16,a0) HD(17,a1) HD(18,a2) HD(19,a3)
        HD(20,a0) HD(21,a1) HD(22,a2) HD(23,a3)
        HD(24,a0) HD(25,a1) HD(26,a2) HD(27,a3)
        HD(28,a0) HD(29,a1) HD(30,a2) HD(31,a3)
        HD(32,a0) HD(33,a1) HD(34,a2) HD(35,a3)
        HD(36,a0) HD(37,a1) HD(38,a2) HD(39,a3)
        HD(40,a0) HD(41,a1) HD(42,a2) HD(43,a3)
        HD(44,a0) HD(45,a1) HD(46,a2) HD(47,a3)
        HD(48,a0) HD(49,a1) HD(50,a2) HD(51,a3)
        HD(52,a0) HD(53,a1) HD(54,a2) HD(55,a3)
        HD(56,a0) HD(57,a1) HD(58,a2) HD(59,a3)
        HD(60,a0) HD(61,a1) HD(62,a2) HD(63,a3)
        const float acc = (a0 + a1) + (a2 + a3);

        // own gate's activation (branch is wave-uniform: wid==2 is g)
        const float av = (wid == 2) ? tanh_fast(acc) : sigm(acc);

        acts[tl & 1][wid][l] = av;
        __syncthreads();

        // x-dot for t+1 in the LDS-read shadow; rotate prefetch to t+2.
        const float xcur = xv;
        float p0 = 0.0f, p1 = 0.0f, p2 = 0.0f, p3 = 0.0f;
        XD(0,p0)  XD(1,p1)  XD(2,p2)  XD(3,p3)
        XD(4,p0)  XD(5,p1)  XD(6,p2)  XD(7,p3)
        XD(8,p0)  XD(9,p1)  XD(10,p2) XD(11,p3)
        XD(12,p0) XD(13,p1) XD(14,p2) XD(15,p3)
        XD(16,p0) XD(17,p1) XD(18,p2) XD(19,p3)
        XD(20,p0) XD(21,p1) XD(22,p2) XD(23,p3)
        XD(24,p0) XD(25,p1) XD(26,p2)
        int tn = t + 2; if (tn > TT - 1) tn = TT - 1;
        xv = (l < IN_) ? x[((size_t)tn * BB + b) * IN_ + l] : 0.0f;
        xpart = (p0 + p1) + (p2 + p3);

        // cell update (redundant across the 4 waves; lane-local)
        const float gi = acts[tl & 1][0][l];
        const float gf = acts[tl & 1][1][l];
        const float gg = acts[tl & 1][2][l];
        const float go = acts[tl & 1][3][l];
        cv = fmaf(gf, cv, gi * gg);
        hv = go * tanh_fast(cv);

        if (wid == 0) {
            *hout = hv;                    // coalesced 256B store per wave
            hout += (size_t)BB * HH;
        }
        // no second barrier: next step writes the OTHER acts buffer; this
        // one is re-written only after the NEXT barrier (see r0/r4 argument).
    }

#undef HD
#undef XD

    if (wid == 0) {
        state[b * HH + l] = hv;
        state[BB * HH + b * HH + l] = cv;
    }
}

// Phase 2: per-timestep BatchNorm (batch stats) + locked dropout + maxpool
// over batch + FC. One block per timestep, fully parallel over tc.
// Unchanged from the verified round-0 kernel.
__global__ __launch_bounds__(256, 2) void bn_pool_fc(
    const float* __restrict__ h_all,  // [tc,B,H]
    const float* __restrict__ gamma,  // [H]
    const float* __restrict__ beta,   // [H]
    const float* __restrict__ dmask,  // [B,H]
    const float* __restrict__ pg,     // [T,OUT]
    const float* __restrict__ W_fc,   // [OUT, H+OUT]
    const float* __restrict__ b_fc,   // [OUT]
    float* __restrict__ y,            // [T,OUT]
    int t0, int tc)
{
    const int tl = blockIdx.x;
    const int t = t0 + tl;
    const int tid = threadIdx.x;
    const int g = tid >> 6;      // 4 batch groups
    const int hcol = tid & 63;
    const float* hp = h_all + (size_t)tl * BB * HH;

    __shared__ float s_a[4][HH];
    __shared__ float s_b[4][HH];
    __shared__ float s_scale[HH];
    __shared__ float s_shift[HH];
    __shared__ float s_pool[HH];

    // pass 1: sum and sumsq over batch (coalesced: lane = hcol)
    float sum = 0.0f, sq = 0.0f;
    for (int bb = g; bb < BB; bb += 4) {
        const float v = hp[bb * HH + hcol];
        sum += v;
        sq = fmaf(v, v, sq);
    }
    s_a[g][hcol] = sum;
    s_b[g][hcol] = sq;
    __syncthreads();

    if (tid < HH) {
        const float s  = (s_a[0][tid] + s_a[1][tid]) + (s_a[2][tid] + s_a[3][tid]);
        const float q2 = (s_b[0][tid] + s_b[1][tid]) + (s_b[2][tid] + s_b[3][tid]);
        const float mean = s * (1.0f / BB);
        const float var  = q2 * (1.0f / BB) - mean * mean;  // biased var
        const float rs = rsqrtf(var + EPSV);
        const float sc = rs * gamma[tid];
        s_scale[tid] = sc;
        s_shift[tid] = beta[tid] - mean * sc;
    }
    __syncthreads();

    // pass 2: normalize + locked dropout + max over batch
    const float sc = s_scale[hcol];
    const float sh = s_shift[hcol];
    float m = -3.0e38f;
    for (int bb = g; bb < BB; bb += 4) {
        const float v = hp[bb * HH + hcol];
        const float hd = fmaf(v, sc, sh) * dmask[bb * HH + hcol];
        m = fmaxf(m, hd);
    }
    s_a[g][hcol] = m;
    __syncthreads();
    if (tid < HH) {
        s_pool[tid] = fmaxf(fmaxf(s_a[0][tid], s_a[1][tid]),
                            fmaxf(s_a[2][tid], s_a[3][tid]));
    }
    __syncthreads();

    // FC: y[t, o] = b_fc[o] + W_fc[o, 0:64].pool + W_fc[o, 64:90].pg[t]
    if (tid < OUTD) {
        float acc = b_fc[tid];
        const float* w = W_fc + tid * (HH + OUTD);
#pragma unroll
        for (int k = 0; k < HH; ++k) acc = fmaf(w[k], s_pool[k], acc);
#pragma unroll
        for (int k = 0; k < OUTD; ++k) acc = fmaf(w[HH + k], pg[t * OUTD + k], acc);
        y[t * OUTD + tid] = acc;
    }
}

extern "C" void kernel_launch(void* const* d_in, const int* in_sizes, int n_in,
                              void* d_out, int out_size, void* d_ws, size_t ws_size,
                              hipStream_t stream)
{
    const float* x     = (const float*)d_in[0];   // [T,B,IN]
    const float* pg    = (const float*)d_in[1];   // [T,OUT]
    const float* W_ih  = (const float*)d_in[2];   // [4H,IN]
    const float* W_hh  = (const float*)d_in[3];   // [4H,H]
    const float* b_ih  = (const float*)d_in[4];
    const float* b_hh  = (const float*)d_in[5];
    const float* gamma = (const float*)d_in[6];
    const float* beta  = (const float*)d_in[7];
    const float* W_fc  = (const float*)d_in[8];   // [OUT,H+OUT]
    const float* b_fc  = (const float*)d_in[9];
    const float* dmask = (const float*)d_in[10];  // [B,H]
    float* y = (float*)d_out;

    // Workspace: h_all[chunkT, B, H] fp32 + carried state h,c [2,B,H].
    const size_t state_bytes = 2ull * BB * HH * sizeof(float);
    const size_t per_t = (size_t)BB * HH * sizeof(float);
    size_t avail = (ws_size > state_bytes) ? (ws_size - state_bytes) : 0;
    int chunkT = (int)(avail / per_t);
    if (chunkT > TT) chunkT = TT;
    if (chunkT < 1) chunkT = 1;

    float* h_all = (float*)d_ws;
    float* state = (float*)((char*)d_ws + (size_t)chunkT * per_t);

    int first = 1;
    for (int t0 = 0; t0 < TT; t0 += chunkT) {
        int tc = TT - t0;
        if (tc > chunkT) tc = chunkT;
        lstm_seq<<<BB, 256, 0, stream>>>(x, W_ih, W_hh, b_ih, b_hh,
                                         h_all, state, t0, tc, first);
        bn_pool_fc<<<tc, 256, 0, stream>>>(h_all, gamma, beta, dmask, pg,
                                           W_fc, b_fc, y, t0, tc);
        first = 0;
    }
}